// Round 1
// baseline (1274.931 us; speedup 1.0000x reference)
//
#include <hip/hip_runtime.h>

// Sorted scatter-add inverted into a per-output-row gather.
// out[n,:] = self[n,:] + sum_{i: idx[i]==n} value[i,:]
// One 64-lane wave per output row; each lane handles 2 columns (float2).
// Segment bounds via wave-uniform binary search on the sorted index.

__global__ __launch_bounds__(256) void scatter_add_gather_kernel(
    const float* __restrict__ self_t,   // [N, 128]
    const float* __restrict__ value,    // [M, 128]
    const int*   __restrict__ idx,      // [M], sorted, values in [0, N)
    float*       __restrict__ out,      // [N, 128]
    int N, int M)
{
    const int D2 = 64;  // D/2 float2 elements per row
    int wave_id = (int)((blockIdx.x * (unsigned)blockDim.x + threadIdx.x) >> 6);
    int lane    = threadIdx.x & 63;
    if (wave_id >= N) return;
    const int n = wave_id;

    // lower_bound(idx, n)  -> seg_lo
    int lo = 0, hi = M;
    while (lo < hi) {
        int mid = (lo + hi) >> 1;
        if (idx[mid] < n) lo = mid + 1; else hi = mid;
    }
    const int seg_lo = lo;
    // lower_bound(idx, n+1) -> seg_hi (continue from seg_lo)
    hi = M;
    while (lo < hi) {
        int mid = (lo + hi) >> 1;
        if (idx[mid] < n + 1) lo = mid + 1; else hi = mid;
    }
    const int seg_hi = lo;

    const float2* selfp = (const float2*)(self_t) + (size_t)n * D2;
    float2 acc = selfp[lane];

    for (int i = seg_lo; i < seg_hi; ++i) {
        const float2* vp = (const float2*)(value) + (size_t)i * D2;
        float2 v = vp[lane];
        acc.x += v.x;
        acc.y += v.y;
    }

    float2* outp = (float2*)(out) + (size_t)n * D2;
    outp[lane] = acc;
}

extern "C" void kernel_launch(void* const* d_in, const int* in_sizes, int n_in,
                              void* d_out, int out_size, void* d_ws, size_t ws_size,
                              hipStream_t stream)
{
    const float* self_t = (const float*)d_in[0];
    const float* value  = (const float*)d_in[1];
    const int*   idx    = (const int*)d_in[2];
    // d_in[3] (pos) unused, matching the reference.
    float* out = (float*)d_out;

    const int D = 128;
    const int N = out_size / D;          // 262144
    const int M = in_sizes[2];           // 1048576

    // one wave (64 threads) per output row, 4 waves per 256-thread block
    const int block = 256;
    const int waves_per_block = block / 64;
    const int grid = (N + waves_per_block - 1) / waves_per_block;

    scatter_add_gather_kernel<<<grid, block, 0, stream>>>(self_t, value, idx, out, N, M);
}

// Round 2
// 762.375 us; speedup vs baseline: 1.6723x; 1.6723x over previous
//
#include <hip/hip_runtime.h>

// Sorted scatter-add as a two-pass gather:
//  Pass A: build CSR row_ptr[N+1] from the sorted index (direct boundary
//          writes, no search): row_ptr[n] = lower_bound(idx, n).
//  Pass B: one 64-lane wave per output row; 2 cached loads for the segment
//          bounds, then stream self row + segment of value rows (float2/lane,
//          up to 4 loads in flight), single coalesced store.

typedef float f2 __attribute__((ext_vector_type(2)));

__global__ __launch_bounds__(256) void build_row_ptr_kernel(
    const int* __restrict__ idx,   // [M], sorted ascending, values in [0,N)
    int*       __restrict__ row_ptr, // [N+1]
    int N, int M)
{
    int i = blockIdx.x * blockDim.x + threadIdx.x;
    if (i > M) return;
    if (i == M) {
        // rows after the last index, plus the sentinel row_ptr[N] = M
        int prev = idx[M - 1];
        for (int n = prev + 1; n <= N; ++n) row_ptr[n] = M;
        return;
    }
    int cur  = idx[i];
    int prev = (i == 0) ? -1 : idx[i - 1];
    for (int n = prev + 1; n <= cur; ++n) row_ptr[n] = i;
}

__global__ __launch_bounds__(256) void gather_add_kernel(
    const float* __restrict__ self_t,   // [N, 128]
    const float* __restrict__ value,    // [M, 128]
    const int*   __restrict__ row_ptr,  // [N+1]
    float*       __restrict__ out,      // [N, 128]
    int N)
{
    const int D2 = 64;  // float2 elements per row
    int wave_id = (int)((blockIdx.x * (unsigned)blockDim.x + threadIdx.x) >> 6);
    int lane    = threadIdx.x & 63;
    if (wave_id >= N) return;
    const int n = wave_id;

    int lo = row_ptr[n];
    int hi = row_ptr[n + 1];
    int cnt = hi - lo;

    const f2* selfp = (const f2*)self_t + (size_t)n * D2 + lane;
    f2 acc = __builtin_nontemporal_load(selfp);

    const f2* vp = (const f2*)value + (size_t)lo * D2 + lane;

    // Unrolled: 4 independent loads in flight, serial adds (matches ref order).
    while (cnt >= 4) {
        f2 v0 = __builtin_nontemporal_load(vp);
        f2 v1 = __builtin_nontemporal_load(vp + D2);
        f2 v2 = __builtin_nontemporal_load(vp + 2 * D2);
        f2 v3 = __builtin_nontemporal_load(vp + 3 * D2);
        acc += v0; acc += v1; acc += v2; acc += v3;
        vp += 4 * D2;
        cnt -= 4;
    }
    while (cnt > 0) {
        f2 v = __builtin_nontemporal_load(vp);
        acc += v;
        vp += D2;
        --cnt;
    }

    f2* outp = (f2*)out + (size_t)n * D2 + lane;
    __builtin_nontemporal_store(acc, outp);
}

// Fallback (ws too small): round-1 binary-search kernel, known-correct.
__global__ __launch_bounds__(256) void scatter_add_bsearch_kernel(
    const float* __restrict__ self_t, const float* __restrict__ value,
    const int* __restrict__ idx, float* __restrict__ out, int N, int M)
{
    const int D2 = 64;
    int wave_id = (int)((blockIdx.x * (unsigned)blockDim.x + threadIdx.x) >> 6);
    int lane    = threadIdx.x & 63;
    if (wave_id >= N) return;
    const int n = wave_id;
    int lo = 0, hi = M;
    while (lo < hi) { int mid = (lo + hi) >> 1; if (idx[mid] < n) lo = mid + 1; else hi = mid; }
    const int seg_lo = lo;
    hi = M;
    while (lo < hi) { int mid = (lo + hi) >> 1; if (idx[mid] < n + 1) lo = mid + 1; else hi = mid; }
    const int seg_hi = lo;
    const f2* selfp = (const f2*)self_t + (size_t)n * D2 + lane;
    f2 acc = *selfp;
    const f2* vp = (const f2*)value + (size_t)seg_lo * D2 + lane;
    for (int i = seg_lo; i < seg_hi; ++i, vp += D2) { f2 v = *vp; acc += v; }
    f2* outp = (f2*)out + (size_t)n * D2 + lane;
    *outp = acc;
}

extern "C" void kernel_launch(void* const* d_in, const int* in_sizes, int n_in,
                              void* d_out, int out_size, void* d_ws, size_t ws_size,
                              hipStream_t stream)
{
    const float* self_t = (const float*)d_in[0];
    const float* value  = (const float*)d_in[1];
    const int*   idx    = (const int*)d_in[2];
    float* out = (float*)d_out;

    const int D = 128;
    const int N = out_size / D;          // 262144
    const int M = in_sizes[2];           // 1048576

    const size_t row_ptr_bytes = (size_t)(N + 1) * sizeof(int);

    if (ws_size >= row_ptr_bytes) {
        int* row_ptr = (int*)d_ws;

        int blockA = 256;
        int gridA  = (M + 1 + blockA - 1) / blockA;
        build_row_ptr_kernel<<<gridA, blockA, 0, stream>>>(idx, row_ptr, N, M);

        int blockB = 256;
        int waves_per_block = blockB / 64;
        int gridB = (N + waves_per_block - 1) / waves_per_block;
        gather_add_kernel<<<gridB, blockB, 0, stream>>>(self_t, value, row_ptr, out, N);
    } else {
        int block = 256;
        int waves_per_block = block / 64;
        int grid = (N + waves_per_block - 1) / waves_per_block;
        scatter_add_bsearch_kernel<<<grid, block, 0, stream>>>(self_t, value, idx, out, N, M);
    }
}